// Round 7
// baseline (536.552 us; speedup 1.0000x reference)
//
#include <hip/hip_runtime.h>
#include <hip/hip_bf16.h>
#include <stdint.h>

#define NN 50000
#define NE 800000
#define CC 96
#define NL 3

// packed-weight geometry: per layer, per tcol: 9 frag-sets (part*3+gate) x 3 ks x 64 lanes x 8 bf16
#define FRAGS_PER_TCOL 1728              // 9*3*64
#define ELEMS_PER_TCOL 13824             // FRAGS*8
#define ELEMS_PER_LAYER 82944            // 6*ELEMS_PER_TCOL

typedef __bf16 bf16x8 __attribute__((ext_vector_type(8)));
typedef float f32x4 __attribute__((ext_vector_type(4)));
typedef uint16_t u16x8 __attribute__((ext_vector_type(8)));

__device__ __forceinline__ uint16_t f2bf(float f){
  uint32_t u = __builtin_bit_cast(uint32_t, f);
  uint32_t r = (u + 0x7fffu + ((u >> 16) & 1u)) >> 16;
  return (uint16_t)r;
}
__device__ __forceinline__ float bf2f(uint16_t h){
  uint32_t u = ((uint32_t)h) << 16;
  return __builtin_bit_cast(float, u);
}
__device__ __forceinline__ void split_bf(float f, uint16_t& hi, uint16_t& lo){
  hi = f2bf(f);
  lo = f2bf(f - bf2f(hi));
}
// load 8 contiguous f32 and split to hi/lo bf16x8 fragments (in-register)
__device__ __forceinline__ void split8(const float* p, bf16x8& h8, bf16x8& l8){
  float4 a = *(const float4*)p;
  float4 b = *(const float4*)(p+4);
  float v[8] = {a.x,a.y,a.z,a.w,b.x,b.y,b.z,b.w};
  #pragma unroll
  for(int j=0;j<8;j++){
    uint16_t hi, lo; split_bf(v[j], hi, lo);
    h8[j] = __builtin_bit_cast(__bf16, hi);
    l8[j] = __builtin_bit_cast(__bf16, lo);
  }
}
__device__ __forceinline__ uint16_t f2h(float f){
  _Float16 h = (_Float16)f;
  return __builtin_bit_cast(uint16_t, h);
}
__device__ __forceinline__ float h2f(uint16_t u){
  return (float)__builtin_bit_cast(_Float16, u);
}

__global__ void k_zero(int* counts, int* gcur){
  int i = blockIdx.x*256 + threadIdx.x;
  if(i < NN) counts[i] = 0;
  if(i == 0) *gcur = 0;
}

__global__ void k_hist(const int* __restrict__ dstv, int* __restrict__ counts){
  int e = blockIdx.x*256 + threadIdx.x;
  if(e < NE) atomicAdd(&counts[dstv[e]], 1);
}

// Scan-free bucket assignment: CSR bucket ORDER is arbitrary — wave-prefix-scan
// counts, one atomicAdd on a global cursor per wave grabs the bucket range.
__global__ void k_assign(const int* __restrict__ counts, int* __restrict__ offsets,
                         int* __restrict__ cursor, int* __restrict__ gcur){
  int i = blockIdx.x*256 + threadIdx.x;
  int lane = threadIdx.x & 63;
  int v = (i < NN) ? counts[i] : 0;
  int sum = v;
  #pragma unroll
  for(int d=1; d<64; d<<=1){
    int t = __shfl_up(sum, d, 64);
    if(lane >= d) sum += t;
  }
  int total = __shfl(sum, 63, 64);
  int base = 0;
  if(lane == 63) base = atomicAdd(gcur, total);
  base = __shfl(base, 63, 64);
  int off = base + sum - v;
  if(i < NN){ offsets[i] = off; cursor[i] = off; }
}

__global__ void k_fill(const int* __restrict__ srcv, const int* __restrict__ dstv,
                       int* __restrict__ cursor, int* __restrict__ ssrc){
  int e = blockIdx.x*256 + threadIdx.x;
  if(e < NE){
    int d = dstv[e];
    int pos = atomicAdd(&cursor[d], 1);
    ssrc[pos] = srcv[e];
  }
}

// f32 -> fp16 copy of x (gather table; halves gather traffic, 2^-11 rel err)
__global__ void k_cvt16(const float4* __restrict__ x, u16x8* __restrict__ xh, int n8){
  int i = blockIdx.x*256 + threadIdx.x;
  if(i < n8){
    float4 a = x[i*2], b = x[i*2+1];
    u16x8 o;
    o[0]=f2h(a.x); o[1]=f2h(a.y); o[2]=f2h(a.z); o[3]=f2h(a.w);
    o[4]=f2h(b.x); o[5]=f2h(b.y); o[6]=f2h(b.z); o[7]=f2h(b.w);
    xh[i] = o;
  }
}

// Pack weights in MFMA-fragment-linear order.
// gw[l][tcol][pg][ks][lane][8], pg = part*3+gate; part 0=Wc_hi, 1=Wc_lo, 2=Whh(hi only).
// B-frag mapping (16x16x32): n = lane&15, k = (lane>>4)*8 + j.
__device__ __forceinline__ size_t frag_elem(int tcol, int part, int g, int ks, int lane, int j){
  return ((size_t)((tcol*9 + part*3 + g)*3 + ks)*64 + lane)*8 + j;
}
__global__ void k_pack_w(const float* __restrict__ weight, const float* __restrict__ w_ih,
                         const float* __restrict__ w_hh, uint16_t* __restrict__ gw){
  int idx = blockIdx.x*256 + threadIdx.x;
  const int TOT1 = NL*288*CC;     // Wc threads: (l, col, k)
  const int TOT2 = 288*CC;        // Whh threads: (col, k) -> replicate to all 3 layers
  if(idx < TOT1){
    int k = idx % CC;
    int col = (idx / CC) % 288;
    int l = idx / (CC*288);
    const float4* wr = (const float4*)(weight + (size_t)(l*CC + k)*CC);
    const float4* ir = (const float4*)(w_ih + (size_t)col*CC);
    float acc = 0.f;
    #pragma unroll 4
    for(int k2=0;k2<CC/4;k2++){
      float4 a = wr[k2], b = ir[k2];
      acc += a.x*b.x + a.y*b.y + a.z*b.z + a.w*b.w;
    }
    uint16_t h, lo; split_bf(acc, h, lo);
    int g = col / 96, cg = col % 96;
    int tcol = cg >> 4, n = cg & 15;
    int ks = k >> 5, r = (k & 31) >> 3, j = k & 7;
    int lane = r*16 + n;
    size_t lb = (size_t)l*ELEMS_PER_LAYER;
    gw[lb + frag_elem(tcol, 0, g, ks, lane, j)] = h;
    gw[lb + frag_elem(tcol, 1, g, ks, lane, j)] = lo;
  } else {
    int idx2 = idx - TOT1;
    if(idx2 < TOT2){
      int k = idx2 % CC;
      int col = idx2 / CC;
      uint16_t h = f2bf(w_hh[(size_t)col*CC + k]);
      int g = col / 96, cg = col % 96;
      int tcol = cg >> 4, n = cg & 15;
      int ks = k >> 5, r = (k & 31) >> 3, j = k & 7;
      int lane = r*16 + n;
      size_t fe = frag_elem(tcol, 2, g, ks, lane, j);
      #pragma unroll
      for(int l=0;l<NL;l++) gw[(size_t)l*ELEMS_PER_LAYER + fe] = h;
    }
  }
}

// CSR aggregation from the fp16 table: thread = (node, c8) with c8 in [0,12);
// 16B u16x8 gathers, 8-wide ssrc prefetch for MLP; f32 accumulate, f32 out.
__global__ void k_aggregate(const u16x8* __restrict__ xh, const int* __restrict__ offsets,
                            const int* __restrict__ counts, const int* __restrict__ ssrc,
                            float* __restrict__ s_f){
  int tid = blockIdx.x*256 + threadIdx.x;
  if(tid >= NN*12) return;
  int n = tid / 12;
  int c8 = tid - n*12;
  int o0 = offsets[n];
  int o1 = o0 + counts[n];
  float a[8];
  #pragma unroll
  for(int t=0;t<8;t++) a[t] = 0.f;
  int j = o0;
  for(; j+8 <= o1; j+=8){
    int s0 = ssrc[j],   s1 = ssrc[j+1], s2 = ssrc[j+2], s3 = ssrc[j+3];
    int s4 = ssrc[j+4], s5 = ssrc[j+5], s6 = ssrc[j+6], s7 = ssrc[j+7];
    u16x8 v0 = xh[(size_t)s0*12 + c8];
    u16x8 v1 = xh[(size_t)s1*12 + c8];
    u16x8 v2 = xh[(size_t)s2*12 + c8];
    u16x8 v3 = xh[(size_t)s3*12 + c8];
    u16x8 v4 = xh[(size_t)s4*12 + c8];
    u16x8 v5 = xh[(size_t)s5*12 + c8];
    u16x8 v6 = xh[(size_t)s6*12 + c8];
    u16x8 v7 = xh[(size_t)s7*12 + c8];
    #pragma unroll
    for(int t=0;t<8;t++)
      a[t] += ((h2f(v0[t])+h2f(v1[t]))+(h2f(v2[t])+h2f(v3[t])))
            + ((h2f(v4[t])+h2f(v5[t]))+(h2f(v6[t])+h2f(v7[t])));
  }
  for(; j < o1; j++){
    u16x8 v = xh[(size_t)ssrc[j]*12 + c8];
    #pragma unroll
    for(int t=0;t<8;t++) a[t] += h2f(v[t]);
  }
  float4 o0v; o0v.x=a[0]; o0v.y=a[1]; o0v.z=a[2]; o0v.w=a[3];
  float4 o1v; o1v.x=a[4]; o1v.y=a[5]; o1v.z=a[6]; o1v.w=a[7];
  float* dst = s_f + (size_t)n*CC + c8*8;
  *(float4*)dst = o0v;
  *(float4*)(dst+4) = o1v;
}

#define MFMA(A,B,C) __builtin_amdgcn_mfma_f32_16x16x32_bf16(A,B,C,0,0,0)

// Fused dual-GEMM + GRU, NO LDS / NO BARRIERS: B-fragments are read directly
// from the fragment-packed global weight table — a wave's frag read is
// lane-contiguous (1KB coalesced) and the 166KB/layer set is L2-resident.
// Waves run independently; TLP hides the L2 latency (R6 lesson: barrier-locked
// phases don't overlap).
__global__ __launch_bounds__(256) void k_gru(
    const float* __restrict__ s_f, const float* __restrict__ xf,
    const uint16_t* __restrict__ gw_l,
    const float* __restrict__ b_ih, const float* __restrict__ b_hh,
    float* __restrict__ out_f, uint16_t* __restrict__ out_h16)
{
  int wave = threadIdx.x >> 6;
  int lane = threadIdx.x & 63;
  int mtile = blockIdx.x*4 + wave;
  if(mtile >= NN/16) return;          // 3125 M-tiles; no barriers -> early return ok
  int nidx = lane & 15;
  int quad = lane >> 4;

  size_t arow = (size_t)(mtile*16 + nidx)*CC;
  bf16x8 ash[3], asl[3], axh[3], axl[3];
  #pragma unroll
  for(int ks=0; ks<3; ks++){
    int ko = ks*32 + quad*8;
    split8(s_f + arow + ko, ash[ks], asl[ks]);
    split8(xf  + arow + ko, axh[ks], axl[ks]);
  }

  #pragma unroll 1
  for(int tcol=0; tcol<6; tcol++){
    f32x4 air = {0.f,0.f,0.f,0.f}, aiz = {0.f,0.f,0.f,0.f}, ain = {0.f,0.f,0.f,0.f};
    f32x4 ahr = {0.f,0.f,0.f,0.f}, ahz = {0.f,0.f,0.f,0.f}, ahn = {0.f,0.f,0.f,0.f};

    #pragma unroll
    for(int ks=0; ks<3; ks++){
      const uint16_t* base = gw_l + (size_t)tcol*ELEMS_PER_TCOL + ((size_t)ks*64 + lane)*8;
      #define BFRAG(part,g) (*reinterpret_cast<const bf16x8*>(base + (size_t)((part)*3+(g))*3*64*8))
      bf16x8 b;
      b = BFRAG(0,0); air = MFMA(ash[ks], b, air); air = MFMA(asl[ks], b, air);
      b = BFRAG(1,0); air = MFMA(ash[ks], b, air);
      b = BFRAG(0,1); aiz = MFMA(ash[ks], b, aiz); aiz = MFMA(asl[ks], b, aiz);
      b = BFRAG(1,1); aiz = MFMA(ash[ks], b, aiz);
      b = BFRAG(0,2); ain = MFMA(ash[ks], b, ain); ain = MFMA(asl[ks], b, ain);
      b = BFRAG(1,2); ain = MFMA(ash[ks], b, ain);
      b = BFRAG(2,0); ahr = MFMA(axh[ks], b, ahr); ahr = MFMA(axl[ks], b, ahr);
      b = BFRAG(2,1); ahz = MFMA(axh[ks], b, ahz); ahz = MFMA(axl[ks], b, ahz);
      b = BFRAG(2,2); ahn = MFMA(axh[ks], b, ahn); ahn = MFMA(axl[ks], b, ahn);
      #undef BFRAG
    }

    int c = tcol*16 + nidx;
    float bir_ = b_ih[c], biz_ = b_ih[CC+c], bin_ = b_ih[2*CC+c];
    float bhr_ = b_hh[c], bhz_ = b_hh[CC+c], bhn_ = b_hh[2*CC+c];

    #pragma unroll
    for(int r=0;r<4;r++){
      int node = mtile*16 + quad*4 + r;  // C/D: row = quad*4 + reg, col = lane&15
      float ir  = air[r] + bir_;
      float iz  = aiz[r] + biz_;
      float in_ = ain[r] + bin_;
      float hr  = ahr[r] + bhr_;
      float hz  = ahz[r] + bhz_;
      float hn  = ahn[r] + bhn_;
      float rg = 1.f/(1.f + __expf(-(ir+hr)));
      float zg = 1.f/(1.f + __expf(-(iz+hz)));
      float nv = in_ + rg*hn;
      float av = fminf(fabsf(nv), 15.f);
      float e2 = __expf(2.f*av);
      float tg = 1.f - 2.f/(e2 + 1.f);
      tg = (nv < 0.f)? -tg : tg;
      size_t oi = (size_t)node*CC + c;
      float hp = xf[oi];
      float h = (1.f - zg)*tg + zg*hp;
      out_f[oi] = h;                    // in-place on xf is safe: read-before-write per lane
      if(out_h16) out_h16[oi] = f2h(h);
    }
  }
}

extern "C" void kernel_launch(void* const* d_in, const int* in_sizes, int n_in,
                              void* d_out, int out_size, void* d_ws, size_t ws_size,
                              hipStream_t stream){
  const float* x0     = (const float*)d_in[0];
  const int*   ei     = (const int*)d_in[1];
  const float* weight = (const float*)d_in[2];
  const float* w_ih   = (const float*)d_in[3];
  const float* w_hh   = (const float*)d_in[4];
  const float* b_ih   = (const float*)d_in[5];
  const float* b_hh   = (const float*)d_in[6];
  float* out = (float*)d_out;

  const int* srcv = ei;        // edge_index[0]
  const int* dstv = ei + NE;   // edge_index[1]

  char* ws = (char*)d_ws;
  size_t off = 0;
  auto carve = [&](size_t bytes)->char*{
    char* p = ws + off;
    off += (bytes + 255) & ~(size_t)255;
    return p;
  };
  int* counts   = (int*)carve((size_t)NN*4);
  int* offsets  = (int*)carve((size_t)NN*4);
  int* cursor   = (int*)carve((size_t)NN*4);
  int* gcur     = (int*)carve(4);
  int* ssrc     = (int*)carve((size_t)NE*4);
  float* s_f    = (float*)carve((size_t)NN*CC*4);
  float* xfA    = (float*)carve((size_t)NN*CC*4);
  uint16_t* xh16A = (uint16_t*)carve((size_t)NN*CC*2);  // fp16 gather table ping
  uint16_t* xh16B = (uint16_t*)carve((size_t)NN*CC*2);  // fp16 gather table pong
  uint16_t* gw  = (uint16_t*)carve((size_t)NL*ELEMS_PER_LAYER*2);

  // CSR build (once — edge structure shared by all 3 layers)
  k_zero<<<(NN+255)/256, 256, 0, stream>>>(counts, gcur);
  k_hist<<<(NE+255)/256, 256, 0, stream>>>(dstv, counts);
  k_assign<<<(NN+255)/256, 256, 0, stream>>>(counts, offsets, cursor, gcur);
  k_fill<<<(NE+255)/256, 256, 0, stream>>>(srcv, dstv, cursor, ssrc);

  // fp16 gather table for layer 0; fold Wc = W @ w_ih^T, fragment-pack weights
  k_cvt16<<<((NN*CC/8)+255)/256, 256, 0, stream>>>((const float4*)x0, (u16x8*)xh16A, NN*CC/8);
  k_pack_w<<<((NL*288*CC + 288*CC)+255)/256, 256, 0, stream>>>(weight, w_ih, w_hh, gw);

  // xf is a single buffer (in-place safe: k_gru reads only its own rows);
  // fp16 tables ping-pong (gather reads one while epilogue writes the other).
  const float* xf_cur = x0;
  uint16_t* xh_cur = xh16A;
  uint16_t* xh_nxt = xh16B;
  for(int l=0; l<NL; l++){
    k_aggregate<<<((NN*12)+255)/256, 256, 0, stream>>>((const u16x8*)xh_cur, offsets, counts, ssrc, s_f);
    float* out_f = (l==NL-1) ? out : xfA;
    uint16_t* oh = (l==NL-1) ? nullptr : xh_nxt;
    k_gru<<<(NN/16 + 3)/4, 256, 0, stream>>>(s_f, xf_cur,
                                             gw + (size_t)l*ELEMS_PER_LAYER,
                                             b_ih, b_hh, out_f, oh);
    xf_cur = out_f;
    uint16_t* t = xh_cur; xh_cur = xh_nxt; xh_nxt = t;
  }
}

// Round 8
// 326.455 us; speedup vs baseline: 1.6436x; 1.6436x over previous
//
#include <hip/hip_runtime.h>
#include <hip/hip_bf16.h>
#include <stdint.h>

#define NN 50000
#define NE 800000
#define CC 96
#define NL 3

// fp16 fragment-packed weights: per layer: 6 tcol x 6 sets (0-2 Wc gates, 3-5 Whh gates)
// x 3 ks x 64 lanes x 8 fp16 = 55296 elems = 108 KB
#define ELEMS_PER_LAYER 55296

typedef _Float16 f16x8 __attribute__((ext_vector_type(8)));
typedef float f32x4 __attribute__((ext_vector_type(4)));
typedef uint16_t u16x8 __attribute__((ext_vector_type(8)));

__device__ __forceinline__ uint16_t f2h(float f){
  _Float16 h = (_Float16)f;
  return __builtin_bit_cast(uint16_t, h);
}
__device__ __forceinline__ float h2f(uint16_t u){
  return (float)__builtin_bit_cast(_Float16, u);
}

__global__ void k_zero(int* counts, int* gcur){
  int i = blockIdx.x*256 + threadIdx.x;
  if(i < NN) counts[i] = 0;
  if(i == 0) *gcur = 0;
}

__global__ void k_hist(const int* __restrict__ dstv, int* __restrict__ counts){
  int e = blockIdx.x*256 + threadIdx.x;
  if(e < NE) atomicAdd(&counts[dstv[e]], 1);
}

// Scan-free bucket assignment (CSR bucket order is arbitrary): wave-prefix-scan
// + one global-cursor atomic per wave.
__global__ void k_assign(const int* __restrict__ counts, int* __restrict__ offsets,
                         int* __restrict__ cursor, int* __restrict__ gcur){
  int i = blockIdx.x*256 + threadIdx.x;
  int lane = threadIdx.x & 63;
  int v = (i < NN) ? counts[i] : 0;
  int sum = v;
  #pragma unroll
  for(int d=1; d<64; d<<=1){
    int t = __shfl_up(sum, d, 64);
    if(lane >= d) sum += t;
  }
  int total = __shfl(sum, 63, 64);
  int base = 0;
  if(lane == 63) base = atomicAdd(gcur, total);
  base = __shfl(base, 63, 64);
  int off = base + sum - v;
  if(i < NN){ offsets[i] = off; cursor[i] = off; }
}

__global__ void k_fill(const int* __restrict__ srcv, const int* __restrict__ dstv,
                       int* __restrict__ cursor, int* __restrict__ ssrc){
  int e = blockIdx.x*256 + threadIdx.x;
  if(e < NE){
    int d = dstv[e];
    int pos = atomicAdd(&cursor[d], 1);
    ssrc[pos] = srcv[e];
  }
}

// f32 -> fp16 table of x (layer-0 gather/GEMM operand table)
__global__ void k_cvt16(const float4* __restrict__ x, u16x8* __restrict__ xh, int n8){
  int i = blockIdx.x*256 + threadIdx.x;
  if(i < n8){
    float4 a = x[i*2], b = x[i*2+1];
    u16x8 o;
    o[0]=f2h(a.x); o[1]=f2h(a.y); o[2]=f2h(a.z); o[3]=f2h(a.w);
    o[4]=f2h(b.x); o[5]=f2h(b.y); o[6]=f2h(b.z); o[7]=f2h(b.w);
    xh[i] = o;
  }
}

// Pack fp16 weights in MFMA-fragment-linear order.
// fe(tcol,g2,ks,lane,j) = (((tcol*6+g2)*3+ks)*64+lane)*8+j; g2: 0-2 Wc r/z/n, 3-5 Whh r/z/n.
// B-frag (16x16x32): element (k = ks*32 + (lane>>4)*8 + j, n = lane&15); B[k][n] multiplies A[m][k].
__device__ __forceinline__ size_t frag_elem(int tcol, int g2, int ks, int lane, int j){
  return (((size_t)(tcol*6 + g2)*3 + ks)*64 + lane)*8 + j;
}
__global__ void k_pack_w(const float* __restrict__ weight, const float* __restrict__ w_ih,
                         const float* __restrict__ w_hh, uint16_t* __restrict__ gw){
  int idx = blockIdx.x*256 + threadIdx.x;
  const int TOT1 = NL*288*CC;     // Wc: (l, col, k)
  const int TOT2 = 288*CC;        // Whh: (col, k), replicated to all layers
  if(idx < TOT1){
    int k = idx % CC;
    int col = (idx / CC) % 288;
    int l = idx / (CC*288);
    // Wc[k][col] = sum_k2 weight[l][k][k2] * w_ih[col][k2]
    const float4* wr = (const float4*)(weight + (size_t)(l*CC + k)*CC);
    const float4* ir = (const float4*)(w_ih + (size_t)col*CC);
    float acc = 0.f;
    #pragma unroll 4
    for(int k2=0;k2<CC/4;k2++){
      float4 a = wr[k2], b = ir[k2];
      acc += a.x*b.x + a.y*b.y + a.z*b.z + a.w*b.w;
    }
    int g = col / 96, cg = col % 96;
    int tcol = cg >> 4, n = cg & 15;
    int ks = k >> 5, r = (k & 31) >> 3, j = k & 7;
    int lane = r*16 + n;
    gw[(size_t)l*ELEMS_PER_LAYER + frag_elem(tcol, g, ks, lane, j)] = f2h(acc);
  } else {
    int idx2 = idx - TOT1;
    if(idx2 < TOT2){
      int k = idx2 % CC;
      int col = idx2 / CC;
      uint16_t h = f2h(w_hh[(size_t)col*CC + k]);   // gh = x @ w_hh^T: B[k][col] = w_hh[col][k]
      int g = col / 96, cg = col % 96;
      int tcol = cg >> 4, n = cg & 15;
      int ks = k >> 5, r = (k & 31) >> 3, j = k & 7;
      int lane = r*16 + n;
      size_t fe = frag_elem(tcol, 3+g, ks, lane, j);
      #pragma unroll
      for(int l=0;l<NL;l++) gw[(size_t)l*ELEMS_PER_LAYER + fe] = h;
    }
  }
}

// CSR aggregation from fp16 table: thread = (node, c8), 16B gathers, 8-wide ssrc
// prefetch; f32 accumulate, fp16 s-table out (feeds k_gru A-frags directly).
__global__ void k_aggregate(const u16x8* __restrict__ xh, const int* __restrict__ offsets,
                            const int* __restrict__ counts, const int* __restrict__ ssrc,
                            u16x8* __restrict__ s16){
  int tid = blockIdx.x*256 + threadIdx.x;
  if(tid >= NN*12) return;
  int n = tid / 12;
  int c8 = tid - n*12;
  int o0 = offsets[n];
  int o1 = o0 + counts[n];
  float a[8];
  #pragma unroll
  for(int t=0;t<8;t++) a[t] = 0.f;
  int j = o0;
  for(; j+8 <= o1; j+=8){
    int s0 = ssrc[j],   s1 = ssrc[j+1], s2 = ssrc[j+2], s3 = ssrc[j+3];
    int s4 = ssrc[j+4], s5 = ssrc[j+5], s6 = ssrc[j+6], s7 = ssrc[j+7];
    u16x8 v0 = xh[(size_t)s0*12 + c8];
    u16x8 v1 = xh[(size_t)s1*12 + c8];
    u16x8 v2 = xh[(size_t)s2*12 + c8];
    u16x8 v3 = xh[(size_t)s3*12 + c8];
    u16x8 v4 = xh[(size_t)s4*12 + c8];
    u16x8 v5 = xh[(size_t)s5*12 + c8];
    u16x8 v6 = xh[(size_t)s6*12 + c8];
    u16x8 v7 = xh[(size_t)s7*12 + c8];
    #pragma unroll
    for(int t=0;t<8;t++)
      a[t] += ((h2f(v0[t])+h2f(v1[t]))+(h2f(v2[t])+h2f(v3[t])))
            + ((h2f(v4[t])+h2f(v5[t]))+(h2f(v6[t])+h2f(v7[t])));
  }
  for(; j < o1; j++){
    u16x8 v = xh[(size_t)ssrc[j]*12 + c8];
    #pragma unroll
    for(int t=0;t<8;t++) a[t] += h2f(v[t]);
  }
  u16x8 o;
  #pragma unroll
  for(int t=0;t<8;t++) o[t] = f2h(a[t]);
  s16[tid] = o;
}

#define MFMA16(A,B,C) __builtin_amdgcn_mfma_f32_16x16x32_f16(A,B,C,0,0,0)

// Fused dual-GEMM + GRU, single-barrier: the ENTIRE fp16 layer weight set
// (108 KB) is staged into LDS once per block; after one __syncthreads each of
// the 16 waves independently processes one mtile (16 nodes x 96 channels):
// 6 A-frag loads (fp16 tables, no conversion), 108 ds_read_b128 + 108 MFMAs.
__global__ __launch_bounds__(1024) void k_gru(
    const uint16_t* __restrict__ s16, const uint16_t* __restrict__ x16,
    const float* __restrict__ xf, const uint16_t* __restrict__ gw_l,
    const float* __restrict__ b_ih, const float* __restrict__ b_hh,
    float* __restrict__ out_f, uint16_t* __restrict__ out_h16)
{
  __shared__ __align__(16) uint16_t lw[ELEMS_PER_LAYER];   // 110592 B

  const int tid = threadIdx.x;
  // stage all 108 KB: 6912 uint4 chunks over 1024 threads
  {
    const uint4* src = (const uint4*)gw_l;
    uint4* dst = (uint4*)lw;
    #pragma unroll
    for(int i=0;i<7;i++){
      int chunk = i*1024 + tid;
      if(chunk < ELEMS_PER_LAYER/8) dst[chunk] = src[chunk];
    }
  }
  __syncthreads();                        // the only barrier

  int wave = tid >> 6;
  int lane = tid & 63;
  int mtile = wave*256 + blockIdx.x;      // cyclic: all 256 blocks/CUs busy
  if(mtile >= NN/16) return;              // no more barriers -> early return ok
  int nidx = lane & 15;
  int quad = lane >> 4;

  // A fragments: direct u16x8 loads from fp16 tables (A: m=lane&15, k=quad*8+j)
  f16x8 as[3], ax[3];
  {
    size_t arow = (size_t)(mtile*16 + nidx)*CC;
    #pragma unroll
    for(int ks=0; ks<3; ks++){
      int ko = ks*32 + quad*8;
      as[ks] = *reinterpret_cast<const f16x8*>(s16 + arow + ko);
      ax[ks] = *reinterpret_cast<const f16x8*>(x16 + arow + ko);
    }
  }

  #pragma unroll 1
  for(int tcol=0; tcol<6; tcol++){
    f32x4 air = {0.f,0.f,0.f,0.f}, aiz = {0.f,0.f,0.f,0.f}, ain = {0.f,0.f,0.f,0.f};
    f32x4 ahr = {0.f,0.f,0.f,0.f}, ahz = {0.f,0.f,0.f,0.f}, ahn = {0.f,0.f,0.f,0.f};

    #pragma unroll
    for(int ks=0; ks<3; ks++){
      const uint16_t* base = lw + (((size_t)tcol*6)*3 + ks)*512 + lane*8;
      #define BFRAG(g2) (*reinterpret_cast<const f16x8*>(base + (size_t)(g2)*3*512))
      air = MFMA16(as[ks], BFRAG(0), air);
      aiz = MFMA16(as[ks], BFRAG(1), aiz);
      ain = MFMA16(as[ks], BFRAG(2), ain);
      ahr = MFMA16(ax[ks], BFRAG(3), ahr);
      ahz = MFMA16(ax[ks], BFRAG(4), ahz);
      ahn = MFMA16(ax[ks], BFRAG(5), ahn);
      #undef BFRAG
    }

    int c = tcol*16 + nidx;
    float bir_ = b_ih[c], biz_ = b_ih[CC+c], bin_ = b_ih[2*CC+c];
    float bhr_ = b_hh[c], bhz_ = b_hh[CC+c], bhn_ = b_hh[2*CC+c];

    #pragma unroll
    for(int r=0;r<4;r++){
      int node = mtile*16 + quad*4 + r;   // C/D: row = quad*4 + reg, col = lane&15
      float ir  = air[r] + bir_;
      float iz  = aiz[r] + biz_;
      float in_ = ain[r] + bin_;
      float hr  = ahr[r] + bhr_;
      float hz  = ahz[r] + bhz_;
      float hn  = ahn[r] + bhn_;
      float rg = 1.f/(1.f + __expf(-(ir+hr)));
      float zg = 1.f/(1.f + __expf(-(iz+hz)));
      float nv = in_ + rg*hn;
      float av = fminf(fabsf(nv), 15.f);
      float e2 = __expf(2.f*av);
      float tg = 1.f - 2.f/(e2 + 1.f);
      tg = (nv < 0.f)? -tg : tg;
      size_t oi = (size_t)node*CC + c;
      float hp = xf[oi];
      float h = (1.f - zg)*tg + zg*hp;
      out_f[oi] = h;          // in-place on xf safe: only same-lane read precedes write
      if(out_h16) out_h16[oi] = f2h(h);
    }
  }
}

extern "C" void kernel_launch(void* const* d_in, const int* in_sizes, int n_in,
                              void* d_out, int out_size, void* d_ws, size_t ws_size,
                              hipStream_t stream){
  const float* x0     = (const float*)d_in[0];
  const int*   ei     = (const int*)d_in[1];
  const float* weight = (const float*)d_in[2];
  const float* w_ih   = (const float*)d_in[3];
  const float* w_hh   = (const float*)d_in[4];
  const float* b_ih   = (const float*)d_in[5];
  const float* b_hh   = (const float*)d_in[6];
  float* out = (float*)d_out;

  const int* srcv = ei;        // edge_index[0]
  const int* dstv = ei + NE;   // edge_index[1]

  char* ws = (char*)d_ws;
  size_t off = 0;
  auto carve = [&](size_t bytes)->char*{
    char* p = ws + off;
    off += (bytes + 255) & ~(size_t)255;
    return p;
  };
  int* counts   = (int*)carve((size_t)NN*4);
  int* offsets  = (int*)carve((size_t)NN*4);
  int* cursor   = (int*)carve((size_t)NN*4);
  int* gcur     = (int*)carve(4);
  int* ssrc     = (int*)carve((size_t)NE*4);
  uint16_t* s16 = (uint16_t*)carve((size_t)NN*CC*2);    // fp16 aggregate table
  float* xfA    = (float*)carve((size_t)NN*CC*4);       // f32 h state (in-place)
  uint16_t* xh16A = (uint16_t*)carve((size_t)NN*CC*2);  // fp16 x table ping
  uint16_t* xh16B = (uint16_t*)carve((size_t)NN*CC*2);  // fp16 x table pong
  uint16_t* gw  = (uint16_t*)carve((size_t)NL*ELEMS_PER_LAYER*2);

  // CSR build (once — edge structure shared by all 3 layers)
  k_zero<<<(NN+255)/256, 256, 0, stream>>>(counts, gcur);
  k_hist<<<(NE+255)/256, 256, 0, stream>>>(dstv, counts);
  k_assign<<<(NN+255)/256, 256, 0, stream>>>(counts, offsets, cursor, gcur);
  k_fill<<<(NE+255)/256, 256, 0, stream>>>(srcv, dstv, cursor, ssrc);

  // fp16 table for layer 0; fold Wc = W @ w_ih^T and fragment-pack (all fp16)
  k_cvt16<<<((NN*CC/8)+255)/256, 256, 0, stream>>>((const float4*)x0, (u16x8*)xh16A, NN*CC/8);
  k_pack_w<<<((NL*288*CC + 288*CC)+255)/256, 256, 0, stream>>>(weight, w_ih, w_hh, gw);

  const float* xf_cur = x0;
  uint16_t* xh_cur = xh16A;
  uint16_t* xh_nxt = xh16B;
  for(int l=0; l<NL; l++){
    k_aggregate<<<((NN*12)+255)/256, 256, 0, stream>>>((const u16x8*)xh_cur, offsets, counts, ssrc, (u16x8*)s16);
    float* out_f = (l==NL-1) ? out : xfA;
    uint16_t* oh = (l==NL-1) ? nullptr : xh_nxt;
    k_gru<<<256, 1024, 0, stream>>>(s16, xh_cur, xf_cur,
                                    gw + (size_t)l*ELEMS_PER_LAYER,
                                    b_ih, b_hh, out_f, oh);
    xf_cur = out_f;
    uint16_t* t = xh_cur; xh_cur = xh_nxt; xh_nxt = t;
  }
}